// Round 1
// baseline (1906.575 us; speedup 1.0000x reference)
//
#include <hip/hip_runtime.h>
#include <cstddef>

#define NS 64
#define NC 32
#define NN 96
#define TT 50
#define BB 256
#define NT 512   // threads per block (8 waves)

// LDS strides (floats). 104 % 32 == 8 -> adjacent padded rows land 8 banks
// apart, killing the stride-96 (==0 mod 32) 4-way conflicts.
#define VS 68
#define QS 104
#define FS 104
#define AS 104

// LDS float offsets
#define OFF_V    0          // 64*68  = 4352
#define OFF_Q    4352       // 96*104 = 9984
#define OFF_F    14336      // 64*104 = 6656
#define OFF_M    20992      // 64*104 = 6656
#define OFF_A    27648      // 32*104 = 3328
#define OFF_PR   30976      // 2 bufs x 4 rows x 104 = 832  (4-wide GJ pivot rows)
#define OFF_PC   31808      // 2 bufs x 4 cols x 32  = 256  (4-wide GJ pivot cols)
#define OFF_XUT  32064      // 96
#define OFF_CV   32160      // 96
#define OFF_QT   32256      // 96
#define OFF_VV   32352      // 64
#define LDS_FLOATS 32416    // 129664 bytes -> still 1 block/CU (grid==CUs)

// Fence-light workgroup barrier: drains LDS (lgkmcnt) but NOT vmcnt, so
// register-destined global prefetches stay in flight across it. All
// cross-thread data inside the step lives in LDS, so lgkmcnt(0)+s_barrier
// is exactly __syncthreads() minus the vmcnt drain. "memory" clobber keeps
// the compiler from moving ds ops across it.
__device__ __forceinline__ void bar() {
    asm volatile("s_waitcnt lgkmcnt(0)\n\ts_barrier" ::: "memory");
}

__device__ __forceinline__ float frcp(float x) {
    float r = __builtin_amdgcn_rcpf(x);
    return r * (2.f - x * r);      // 1 Newton step ~ IEEE rcp
}

extern "C" __global__ __launch_bounds__(NT, 1)
void lqr_fused(const float* __restrict__ x_init,
               const float* __restrict__ Cg, const float* __restrict__ cg,
               const float* __restrict__ Fg, const float* __restrict__ cxg,
               const float* __restrict__ cug, float* __restrict__ Kg,
               float* __restrict__ kg, float* __restrict__ out)
{
    extern __shared__ float sm[];
    float* Vb   = sm + OFF_V;
    float* Qb   = sm + OFF_Q;
    float* Fb   = sm + OFF_F;
    float* Mb   = sm + OFF_M;
    float* Ab   = sm + OFF_A;
    float* PRb  = sm + OFF_PR;     // [2][4][104]
    float* PCb  = sm + OFF_PC;     // [2][4][32]
    float* xut  = sm + OFF_XUT;
    float* cv   = sm + OFF_CV;
    float* qtv  = sm + OFF_QT;
    float* vv   = sm + OFF_VV;

    const int b   = blockIdx.x;
    const int tid = threadIdx.x;

    float4 creg[5];   // C_t, pipelined one full t-step ahead
    float4 fnew[3];
    float  xreg = 0.f, cvreg = 0.f;

    // ================= preloop: stage F/xut/c for t=49; load C(49); zero V,v =====
    {
        const int t = TT - 1;
        const float* Fsrc = Fg + ((size_t)t * BB + b) * (NS * NN);
        #pragma unroll
        for (int rr = 0; rr < 3; ++rr) {
            int f = tid + NT * rr;                 // < 1536
            float4 val = ((const float4*)Fsrc)[f];
            int row = f / 24, c4 = f % 24;
            *(float4*)&Fb[row * FS + 4 * c4] = val;
        }
        const float* Csrc = Cg + ((size_t)t * BB + b) * (NN * NN);
        #pragma unroll
        for (int rr = 0; rr < 4; ++rr) creg[rr] = ((const float4*)Csrc)[tid + NT * rr];
        if (tid < 256) creg[4] = ((const float4*)Csrc)[tid + 2048];

        if (tid < NN) {
            xut[tid] = (tid < NS) ? cxg[((size_t)t * BB + b) * NS + tid]
                                  : cug[((size_t)t * BB + b) * NC + (tid - NS)];
            cv[tid] = cg[((size_t)t * BB + b) * NN + tid];
        }
        for (int e = tid; e < NS * VS; e += NT) Vb[e] = 0.f;
        if (tid < NS) vv[tid] = 0.f;
    }
    bar();

    // ================= backward Riccati scan =================
    for (int t = TT - 1; t >= 0; --t) {
        // ---- A: write pipelined C regs -> Qb (loaded a full step ago)
        #pragma unroll
        for (int rr = 0; rr < 5; ++rr) {
            if (rr < 4 || tid < 256) {
                int f = tid + NT * rr;
                int row = f / 24, c4 = f % 24;
                *(float4*)&Qb[row * QS + 4 * c4] = creg[rr];
            }
        }
        // ---- B: issue global loads for t-1 (stay in flight across bar()s)
        if (t > 0) {
            const float* Cs = Cg + ((size_t)(t - 1) * BB + b) * (NN * NN);
            #pragma unroll
            for (int rr = 0; rr < 4; ++rr) creg[rr] = ((const float4*)Cs)[tid + NT * rr];
            if (tid < 256) creg[4] = ((const float4*)Cs)[tid + 2048];
            const float* Fs = Fg + ((size_t)(t - 1) * BB + b) * (NS * NN);
            #pragma unroll
            for (int rr = 0; rr < 3; ++rr) fnew[rr] = ((const float4*)Fs)[tid + NT * rr];
            if (tid < NN) {
                xreg  = (tid < NS) ? cxg[((size_t)(t - 1) * BB + b) * NS + tid]
                                   : cug[((size_t)(t - 1) * BB + b) * NC + (tid - NS)];
                cvreg = cg[((size_t)(t - 1) * BB + b) * NN + tid];
            }
        }

        // ---- P1: M = V @ F  (tile 2 rows x 6 cols; V/F reads broadcast across lanes)
        {
            const int ty = tid >> 4, tx = tid & 15;
            const int i0 = 2 * ty, j0 = 6 * tx;
            float acc[2][6];
            #pragma unroll
            for (int a = 0; a < 2; ++a)
                #pragma unroll
                for (int q = 0; q < 6; ++q) acc[a][q] = 0.f;
            for (int k = 0; k < NS; k += 4) {
                float4 v0 = *(const float4*)&Vb[i0 * VS + k];
                float4 v1 = *(const float4*)&Vb[(i0 + 1) * VS + k];
                #pragma unroll
                for (int dk = 0; dk < 4; ++dk) {
                    float2 f0 = *(const float2*)&Fb[(k + dk) * FS + j0];
                    float2 f1 = *(const float2*)&Fb[(k + dk) * FS + j0 + 2];
                    float2 f2 = *(const float2*)&Fb[(k + dk) * FS + j0 + 4];
                    float fv[6] = {f0.x, f0.y, f1.x, f1.y, f2.x, f2.y};
                    float a0k = (&v0.x)[dk], a1k = (&v1.x)[dk];
                    #pragma unroll
                    for (int q = 0; q < 6; ++q) {
                        acc[0][q] += a0k * fv[q];
                        acc[1][q] += a1k * fv[q];
                    }
                }
            }
            #pragma unroll
            for (int a = 0; a < 2; ++a) {
                *(float2*)&Mb[(i0 + a) * FS + j0]     = make_float2(acc[a][0], acc[a][1]);
                *(float2*)&Mb[(i0 + a) * FS + j0 + 2] = make_float2(acc[a][2], acc[a][3]);
                *(float2*)&Mb[(i0 + a) * FS + j0 + 4] = make_float2(acc[a][4], acc[a][5]);
            }
        }
        bar();   // BAR1: C in Qb, M ready

        // ---- P2a: qt = c + C^T xut + F^T v  (384 threads: 4 lanes per column,
        //      i interleaved stride-4 so the 4 slices land 8 banks apart)
        if (tid < 384) {
            const int j = tid >> 2, s = tid & 3;
            float acc = (s == 0) ? cv[j] : 0.f;
            #pragma unroll 4
            for (int it = 0; it < 24; ++it) {
                int i = 4 * it + s;
                acc += Qb[i * QS + j] * xut[i];
            }
            #pragma unroll 4
            for (int it = 0; it < 16; ++it) {
                int i = 4 * it + s;
                acc += Fb[i * FS + j] * vv[i];
            }
            acc += __shfl_down(acc, 1);
            acc += __shfl_down(acc, 2);
            if (s == 0) {
                qtv[j] = acc;
                if (j >= NS) Ab[(j - NS) * AS + 96] = acc;   // q_u
            }
        }
        bar();   // BAR1.5: all C reads done before in-place overwrite

        // ---- P2b: Q = C + F^T M (in place), dual-write ctrl rows into aug ----
        {
            const int ty = tid >> 4, tx = tid & 15;
            const int a0 = 3 * ty, b0 = 6 * tx;     // 3 rows x 6 cols
            float acc[3][6];
            #pragma unroll
            for (int dr = 0; dr < 3; ++dr) {
                float2 q0 = *(const float2*)&Qb[(a0 + dr) * QS + b0];
                float2 q1 = *(const float2*)&Qb[(a0 + dr) * QS + b0 + 2];
                float2 q2 = *(const float2*)&Qb[(a0 + dr) * QS + b0 + 4];
                acc[dr][0] = q0.x; acc[dr][1] = q0.y; acc[dr][2] = q1.x;
                acc[dr][3] = q1.y; acc[dr][4] = q2.x; acc[dr][5] = q2.y;
            }
            for (int i = 0; i < NS; ++i) {
                float fa0 = Fb[i * FS + a0];
                float fa1 = Fb[i * FS + a0 + 1];
                float fa2 = Fb[i * FS + a0 + 2];
                float2 m0 = *(const float2*)&Mb[i * FS + b0];
                float2 m1 = *(const float2*)&Mb[i * FS + b0 + 2];
                float2 m2 = *(const float2*)&Mb[i * FS + b0 + 4];
                float mb[6] = {m0.x, m0.y, m1.x, m1.y, m2.x, m2.y};
                float fa[3] = {fa0, fa1, fa2};
                #pragma unroll
                for (int dr = 0; dr < 3; ++dr)
                    #pragma unroll
                    for (int q = 0; q < 6; ++q) acc[dr][q] += fa[dr] * mb[q];
            }
            #pragma unroll
            for (int dr = 0; dr < 3; ++dr) {
                *(float2*)&Qb[(a0 + dr) * QS + b0]     = make_float2(acc[dr][0], acc[dr][1]);
                *(float2*)&Qb[(a0 + dr) * QS + b0 + 2] = make_float2(acc[dr][2], acc[dr][3]);
                *(float2*)&Qb[(a0 + dr) * QS + b0 + 4] = make_float2(acc[dr][4], acc[dr][5]);
                int row = a0 + dr;
                if (row >= NS) {                        // aug row: [Q_uu | Q_ux]
                    int rr = row - NS;
                    #pragma unroll
                    for (int q = 0; q < 6; ++q) {
                        int c  = b0 + q;
                        int ac = (c < NS) ? (c + NC) : (c - NS);
                        Ab[rr * AS + ac] = acc[dr][q];
                    }
                }
            }
        }
        bar();   // BAR2: Q and aug ready; Fb free

        // ---- stage F/xut/c for t-1 (overlaps GJ region) ----
        if (t > 0) {
            #pragma unroll
            for (int rr = 0; rr < 3; ++rr) {
                int f = tid + NT * rr;
                int row = f / 24, c4 = f % 24;
                *(float4*)&Fb[row * FS + 4 * c4] = fnew[rr];
            }
            if (tid < NN) { xut[tid] = xreg; cv[tid] = cvreg; }
        }

        // ---- GJ: 4-wide panel Gauss-Jordan. 4 pivots per barrier round:
        //      every thread redundantly reconstructs the 3 intermediate pivot
        //      rows on its own 6-col slice (identical arithmetic order to the
        //      sequential version -> bitwise-equal results). 33 bars -> 9.
        float myinv = 0.f;
        {
            const int g = tid & 15, r = tid >> 4;   // r 0..31, g 0..15
            const int jlo = 6 * g;
            float a[6], a6;
            #pragma unroll
            for (int q = 0; q < 6; ++q) a[q] = Ab[r * AS + jlo + q];
            a6 = (g == 15) ? Ab[r * AS + 96] : 0.f;
            // init publish: rows 0..3 and cols 0..3 (raw)
            if (r < 4) {
                #pragma unroll
                for (int q = 0; q < 6; ++q) PRb[r * 104 + jlo + q] = a[q];
                if (g == 15) PRb[r * 104 + 96] = a6;
            }
            if (g == 0) {
                #pragma unroll
                for (int i = 0; i < 4; ++i) PCb[i * 32 + r] = a[i];
            }
            bar();   // GJ init barrier

            for (int rnd = 0; rnd < 8; ++rnd) {
                const int p0 = 4 * rnd;
                const float* PRc = PRb + (rnd & 1) * 416;
                const float* PCc = PCb + (rnd & 1) * 128;
                float* PRn = PRb + ((rnd + 1) & 1) * 416;
                float* PCn = PCb + ((rnd + 1) & 1) * 128;

                // broadcast scalar taps
                float W0p0 = PRc[0 * 104 + p0 + 0];
                float W0p1 = PRc[0 * 104 + p0 + 1];
                float W0p2 = PRc[0 * 104 + p0 + 2];
                float W0p3 = PRc[0 * 104 + p0 + 3];
                float R1p1 = PRc[1 * 104 + p0 + 1];
                float R1p2 = PRc[1 * 104 + p0 + 2];
                float R1p3 = PRc[1 * 104 + p0 + 3];
                float R2p2 = PRc[2 * 104 + p0 + 2];
                float R2p3 = PRc[2 * 104 + p0 + 3];
                float R3p3 = PRc[3 * 104 + p0 + 3];
                float C0p1 = PCc[0 * 32 + p0 + 1];
                float C0p2 = PCc[0 * 32 + p0 + 2];
                float C0p3 = PCc[0 * 32 + p0 + 3];
                float C1p2 = PCc[1 * 32 + p0 + 2];
                float C1p3 = PCc[1 * 32 + p0 + 3];
                float C2p3 = PCc[2 * 32 + p0 + 3];

                // pivot chain (redundant per thread; ~25 FLOPs)
                float r0 = frcp(W0p0);
                float g1 = C0p1 * r0;                        // fac0(row p1)
                float W1p1 = R1p1 - g1 * W0p1;               // piv1
                float r1 = frcp(W1p1);
                float W1p2 = R1p2 - g1 * W0p2;
                float W1p3 = R1p3 - g1 * W0p3;
                float h0 = C0p2 * r0;                        // fac0(row p2)
                float h1 = (C1p2 - h0 * W0p1) * r1;          // fac1(row p2)
                float W2p2 = R2p2 - h0 * W0p2 - h1 * W1p2;   // piv2
                float r2 = frcp(W2p2);
                float W2p3 = R2p3 - h0 * W0p3 - h1 * W1p3;
                float k0 = C0p3 * r0;
                float k1 = (C1p3 - k0 * W0p1) * r1;
                float k2 = (C2p3 - k0 * W0p2 - k1 * W1p2) * r2;
                float W3p3 = R3p3 - k0 * W0p3 - k1 * W1p3 - k2 * W2p3;  // piv3
                float r3 = frcp(W3p3);

                // my row's factor chain
                float c0 = PCc[0 * 32 + r];
                float c1 = PCc[1 * 32 + r];
                float c2 = PCc[2 * 32 + r];
                float c3 = PCc[3 * 32 + r];
                float fac0 = (r == p0)     ? 0.f : c0 * r0;
                float a1   = c1 - fac0 * W0p1;
                float fac1 = (r == p0 + 1) ? 0.f : a1 * r1;
                float a2   = c2 - fac0 * W0p2 - fac1 * W1p2;
                float fac2 = (r == p0 + 2) ? 0.f : a2 * r2;
                float a3   = c3 - fac0 * W0p3 - fac1 * W1p3 - fac2 * W2p3;
                float fac3 = (r == p0 + 3) ? 0.f : a3 * r3;

                if (r == p0)     myinv = r0;
                if (r == p0 + 1) myinv = r1;
                if (r == p0 + 2) myinv = r2;
                if (r == p0 + 3) myinv = r3;

                // slice update (sequential order == old per-pivot order)
                #pragma unroll
                for (int q = 0; q < 6; ++q) {
                    float w0  = PRc[0 * 104 + jlo + q];
                    float w1r = PRc[1 * 104 + jlo + q];
                    float w2r = PRc[2 * 104 + jlo + q];
                    float w3r = PRc[3 * 104 + jlo + q];
                    float w1 = w1r - g1 * w0;
                    float w2 = w2r - h0 * w0 - h1 * w1;
                    float w3 = w3r - k0 * w0 - k1 * w1 - k2 * w2;
                    a[q] -= fac0 * w0;
                    a[q] -= fac1 * w1;
                    a[q] -= fac2 * w2;
                    a[q] -= fac3 * w3;
                }
                if (g == 15) {
                    float w0  = PRc[0 * 104 + 96];
                    float w1 = PRc[1 * 104 + 96] - g1 * w0;
                    float w2 = PRc[2 * 104 + 96] - h0 * w0 - h1 * w1;
                    float w3 = PRc[3 * 104 + 96] - k0 * w0 - k1 * w1 - k2 * w2;
                    a6 -= fac0 * w0;
                    a6 -= fac1 * w1;
                    a6 -= fac2 * w2;
                    a6 -= fac3 * w3;
                }

                if (rnd < 7) {
                    const int np0 = p0 + 4;
                    // publish next 4 pivot rows (updated through pivot p0+3)
                    if (r >= np0 && r < np0 + 4) {
                        float* dst = PRn + (r - np0) * 104;
                        #pragma unroll
                        for (int q = 0; q < 6; ++q) dst[jlo + q] = a[q];
                        if (g == 15) dst[96] = a6;
                    }
                    // publish next 4 pivot columns
                    #pragma unroll
                    for (int q = 0; q < 6; ++q) {
                        int c = jlo + q;
                        if (c >= np0 && c < np0 + 4) PCn[(c - np0) * 32 + r] = a[q];
                    }
                    bar();   // GJ round barrier (7 total)
                }
            }
            // write back scaled RHS: aug[:,32:97] = [K | kt]
            #pragma unroll
            for (int q = 0; q < 6; ++q) {
                int j = jlo + q;
                if (j >= NC) Ab[r * AS + j] = -a[q] * myinv;
            }
            if (g == 15) Ab[r * AS + 96] = -a6 * myinv;
        }
        bar();   // BAR4: K,kt in Ab

        // ---- store K,kt; P5: Vn = Q_xx + Q_xu K; vn ----
        {
            float* Kt = Kg + ((size_t)t * BB + b) * (NC * NS);
            for (int e = tid; e < NC * NS; e += NT) {
                int m = e >> 6, x = e & 63;
                Kt[e] = Ab[m * AS + 32 + x];
            }
            if (tid < NC) kg[((size_t)t * BB + b) * NC + tid] = Ab[tid * AS + 96];
        }
        {
            const int ty = tid >> 4, tx = tid & 15;
            const int i0 = 2 * ty, j0 = 4 * tx;     // 2 rows x 4 cols
            float acc[2][4];
            #pragma unroll
            for (int di = 0; di < 2; ++di) {
                float4 q = *(const float4*)&Qb[(i0 + di) * QS + j0];
                acc[di][0] = q.x; acc[di][1] = q.y; acc[di][2] = q.z; acc[di][3] = q.w;
            }
            for (int m = 0; m < NC; ++m) {
                float2 qx = *(const float2*)&Qb[(NS + m) * QS + i0];  // Q_xu via symmetry
                float4 kk = *(const float4*)&Ab[m * AS + 32 + j0];
                float kv[4] = {kk.x, kk.y, kk.z, kk.w};
                #pragma unroll
                for (int dj = 0; dj < 4; ++dj) {
                    acc[0][dj] += qx.x * kv[dj];
                    acc[1][dj] += qx.y * kv[dj];
                }
            }
            #pragma unroll
            for (int di = 0; di < 2; ++di)
                *(float4*)&Vb[(i0 + di) * VS + j0] =
                    make_float4(acc[di][0], acc[di][1], acc[di][2], acc[di][3]);
        }
        if (tid < NS) {
            float s0 = qtv[tid], s1 = 0.f;
            for (int m = 0; m < NC; m += 2) {
                s0 += Qb[(NS + m) * QS + tid] * Ab[m * AS + 96];
                s1 += Qb[(NS + m + 1) * QS + tid] * Ab[(m + 1) * AS + 96];
            }
            vv[tid] = s0 + s1;
        }
        bar();   // BAR5: end of t-step
    }

    // ===== bwd->fwd boundary: full fence. Drain this wave's K/k global stores,
    // then a REAL __syncthreads so every wave's stores are visible before any
    // wave reads Kg/kg back in the rollout.
    asm volatile("s_waitcnt vmcnt(0)" ::: "memory");
    __syncthreads();

    // ================= fused forward rollout (tid<256 compute; all hit barriers) ===
    {
        float* xpp = sm;          // [2][96]
        float* dxs = sm + 192;    // [2][64]
        float* out_x = out;                            // T*B*64
        float* out_u = out + (size_t)TT * BB * NS;     // T*B*32

        if (tid < NS) { xpp[tid] = x_init[(size_t)b * NS + tid]; dxs[tid] = 0.f; }
        bar();

        const int mK = tid >> 3, qK = tid & 7;   // u-phase: 32 rows x 8 lanes
        const int iF = tid >> 2, qF = tid & 3;   // x-phase: 64 rows x 4 lanes
        float kr[8], fr[24];
        if (tid < 256) {
            const float* Ksrc = Kg + (size_t)b * (NC * NS);
            #pragma unroll
            for (int xx = 0; xx < 8; ++xx) kr[xx] = Ksrc[mK * NS + qK + 8 * xx];
            const float* Fsrc = Fg + (size_t)b * (NS * NN);
            #pragma unroll
            for (int jj = 0; jj < 24; ++jj) fr[jj] = Fsrc[iF * NN + qF + 4 * jj];
        }

        for (int t = 0; t < TT; ++t) {
            const int cur = (t & 1) * 96, nxt = ((t + 1) & 1) * 96;
            const int curd = (t & 1) * 64, nxtd = ((t + 1) & 1) * 64;
            float krn[8], frn[24];
            if (tid < 256) {
                int tn = (t + 1 < TT) ? (t + 1) : t;
                const float* Ksrc = Kg + ((size_t)tn * BB + b) * (NC * NS);
                #pragma unroll
                for (int xx = 0; xx < 8; ++xx) krn[xx] = Ksrc[mK * NS + qK + 8 * xx];
                const float* Fsrc = Fg + ((size_t)tn * BB + b) * (NS * NN);
                #pragma unroll
                for (int jj = 0; jj < 24; ++jj) frn[jj] = Fsrc[iF * NN + qF + 4 * jj];
            }
            if (tid < NS) out_x[((size_t)t * BB + b) * NS + tid] = xpp[cur + tid];
            if (tid < 256) {
                float s = 0.f;
                #pragma unroll
                for (int xx = 0; xx < 8; ++xx) s += kr[xx] * dxs[curd + qK + 8 * xx];
                s += __shfl_down(s, 4); s += __shfl_down(s, 2); s += __shfl_down(s, 1);
                if (qK == 0) {
                    float un = s + cug[((size_t)t * BB + b) * NC + mK]
                                 + kg[((size_t)t * BB + b) * NC + mK];
                    xpp[cur + NS + mK] = un;
                    out_u[((size_t)t * BB + b) * NC + mK] = un;
                }
            }
            bar();
            if (tid < 256) {
                float s = 0.f;
                #pragma unroll
                for (int jj = 0; jj < 24; ++jj) s += fr[jj] * xpp[cur + qF + 4 * jj];
                s += __shfl_down(s, 2); s += __shfl_down(s, 1);
                if (qF == 0) {
                    float xr = (t + 1 < TT) ? cxg[((size_t)(t + 1) * BB + b) * NS + iF] : 0.f;
                    xpp[nxt + iF] = s;
                    dxs[nxtd + iF] = s - xr;
                }
                #pragma unroll
                for (int xx = 0; xx < 8; ++xx) kr[xx] = krn[xx];
                #pragma unroll
                for (int jj = 0; jj < 24; ++jj) fr[jj] = frn[jj];
            }
            bar();
        }
    }
}

extern "C" void kernel_launch(void* const* d_in, const int* in_sizes, int n_in,
                              void* d_out, int out_size, void* d_ws, size_t ws_size,
                              hipStream_t stream)
{
    const float* x_init = (const float*)d_in[0];
    const float* Cg     = (const float*)d_in[1];
    const float* cg     = (const float*)d_in[2];
    const float* Fg     = (const float*)d_in[3];
    const float* cxg    = (const float*)d_in[4];
    const float* cug    = (const float*)d_in[5];
    float* out = (float*)d_out;

    float* Kg = (float*)d_ws;                              // T*B*32*64 floats
    float* kg = Kg + (size_t)TT * BB * NC * NS;            // T*B*32 floats

    hipFuncSetAttribute((const void*)lqr_fused,
                        hipFuncAttributeMaxDynamicSharedMemorySize,
                        LDS_FLOATS * 4);

    lqr_fused<<<BB, NT, LDS_FLOATS * 4, stream>>>(x_init, Cg, cg, Fg, cxg, cug,
                                                  Kg, kg, out);
}